// Round 1
// baseline (2511.911 us; speedup 1.0000x reference)
//
#include <hip/hip_runtime.h>

// GeneralLinear: x[8192,16,576] fp32 -> out[8192,16,9] fp32.
// out[n,o,col_l(e)] = (1/32) * sum_{c,u} x[n, c, off_l + u*d_l + e] * w_l[c*64+u, o]
//
// R5 structure (counted-vmcnt pipeline, no workspace):
//  - 512 identical blocks: (tile of 128 rows, cp in 0..3 -> 4 channels, g in 0..1 ->
//    u-range [32g, 32g+32) of EVERY l). Symmetric split: no g0/g1 imbalance.
//  - Stage = 16 rows x 1 channel x 288 cols (the block's u-slice of l0+l1+l2),
//    gathered by global_load_lds (per-lane source addresses) into a col-major-
//    float4 LDS layout [72 qcols][16 rows][4]: every DMA instr writes a linear
//    1 KB LDS run while reading 16 rows x 64 B aligned contiguous from HBM;
//    compute reads are 16 consecutive b128 per instr -> 2-way bank alias (free).
//    No padding, no exec-masked DMA lanes.
//  - 3 stage buffers, depth-2 prefetch. Per stage: per-wave counted
//    s_waitcnt vmcnt(W) (W = own in-flight DMAs for ONE stage: 5 for waves 0-1,
//    4 for waves 2-3) -> s_barrier -> compute -> [epilogue] -> issue(s+2).
//    vmcnt never drains to 0 inside the loop (only the final stage).
//  - 4 channels accumulate in registers (acc[9] float4); epilogue once per
//    rowgroup = direct fp32 atomicAdd into out (32 adds/cell total across
//    4 waves x 4 cp x 2 g). Zero epilogue barriers, no REDO, no ws, no
//    reduce kernel. out zeroed via hipMemsetAsync (graph-capture safe).

#define NROWS 8192
#define DIN   576
#define XROW  (16 * DIN)          // 9216 floats per x row
#define RPB   128                 // rows per block
#define NRG   8                   // rowgroups of 16
#define NSTG  32                  // 8 rowgroups x 4 channels
#define SFL   4608                // stage buffer floats (72 qc x 16 r x 4)
#define WOFF  (3 * SFL)           // 13824: weights after 3 x-buffers
#define LDSF  (WOFF + 6144)       // 19968 floats = 79872 B -> 2 blocks/CU

__device__ __forceinline__ void dma16(const float* g, float* l) {
    __builtin_amdgcn_global_load_lds(
        (const __attribute__((address_space(1))) void*)g,
        (__attribute__((address_space(3))) void*)l, 16, 0, 0);
}

__device__ __forceinline__ void fma4(float4& a, float s, const float4 w) {
    a.x += s * w.x; a.y += s * w.y; a.z += s * w.z; a.w += s * w.w;
}

__global__ __launch_bounds__(256, 2) void glin_fused(
    const float* __restrict__ x,
    const float* __restrict__ w0,
    const float* __restrict__ w1,
    const float* __restrict__ w2,
    float* __restrict__ out)
{
    __shared__ __align__(16) float lds[LDSF];
#define LD4(i) (*(const float4*)&lds[(i)])

    const int tid  = threadIdx.x;
    const int lane = tid & 63;
    const int wv   = tid >> 6;
    const int r    = lane & 15;    // row within rowgroup
    const int oq   = lane >> 4;    // output quad (o = oq*4 + j)
    const int b    = blockIdx.x;
    const int tile = b & 63;
    const int cp   = (b >> 6) & 3; // channels 4cp..4cp+3
    const int g    = b >> 8;       // u-range [32g, 32g+32)
    const int rowbase = tile * RPB;

    // ---- prologue: weights, 24 DMA instrs (6 per wave) ----
    // layout: [l(3)][cl(4)][lu(32)][o(16)], chunk (l,cl) = 512 floats contiguous
#pragma unroll
    for (int i = 0; i < 6; ++i) {
        const int j = wv * 6 + i, t = j >> 1, h = j & 1, l = t >> 2, cl = t & 3;
        const float* wl = (l == 0) ? w0 : (l == 1) ? w1 : w2;
        dma16(wl + ((4 * cp + cl) * 64 + 32 * g) * 16 + h * 256 + lane * 4,
              &lds[WOFF + t * 512 + h * 256]);
    }

    // stage DMA: 18 instrs/block; wave wv issues {wv, wv+4, wv+8, wv+12}(+16+wv if wv<2)
    // dest flat float index d = i*256 + lane*4; qc = i*4 + oq, row = r.
    auto issue = [&](int s, int buf) {
        const int rg = s >> 2, c = cp * 4 + (s & 3);
        const float* xb = x + (size_t)(rowbase + rg * 16 + r) * XROW + c * DIN;
        float* db = &lds[buf * SFL];
#pragma unroll
        for (int k = 0; k < 4; ++k) {
            const int i  = wv + k * 4;
            const int qc = i * 4 + oq, lc = qc * 4;
            const int col = (qc < 8)  ? (32 * g + lc)          // l0 slice
                          : (qc < 32) ? (32 + 96 * g + lc)     // l1 slice
                                      : (128 + 160 * g + lc);  // l2 slice
            dma16(xb + col, db + i * 256);
        }
        if (wv < 2) {
            const int i  = 16 + wv;
            const int lc = (i * 4 + oq) * 4;
            dma16(xb + 128 + 160 * g + lc, db + i * 256);      // qc 64..71: l2 tail
        }
    };

    issue(0, 0);
    issue(1, 1);

    float4 acc[9];
    const float sc = 1.0f / 32.0f;
    int buf = 0;

    for (int rg = 0; rg < NRG; ++rg) {
#pragma unroll
        for (int ch = 0; ch < 4; ++ch) {
            const int s = rg * 4 + ch;

            // certify OWN stage-s DMAs landed, THEN align all waves (race-free:
            // after the barrier, every wave's stage-s loads are complete).
            if (s == NSTG - 1)   asm volatile("s_waitcnt vmcnt(0)" ::: "memory");
            else if (wv < 2)     asm volatile("s_waitcnt vmcnt(5)" ::: "memory");
            else                 asm volatile("s_waitcnt vmcnt(4)" ::: "memory");
            __builtin_amdgcn_s_barrier();
            asm volatile("" ::: "memory");

            if (ch == 0) {
#pragma unroll
                for (int i = 0; i < 9; ++i) acc[i] = make_float4(0.f, 0.f, 0.f, 0.f);
            }

            const int xo = buf * SFL + r * 4;
            const int wq = WOFF + ch * 512 + oq * 4;
#pragma unroll
            for (int qq = 0; qq < 2; ++qq) {
                const int q = wv * 2 + qq;       // local u-quad: u = 32g + 4q + i
                {   // l0 -> acc[0]
                    const int wa = wq + q * 64;
                    float4 xq = LD4(xo + q * 64);
                    float4 a0 = LD4(wa), a1 = LD4(wa + 16),
                           a2 = LD4(wa + 32), a3 = LD4(wa + 48);
                    fma4(acc[0], xq.x, a0); fma4(acc[0], xq.y, a1);
                    fma4(acc[0], xq.z, a2); fma4(acc[0], xq.w, a3);
                }
                {   // l1 -> acc[1..3]
                    const int wa = wq + 2048 + q * 64;
                    const int x1 = xo + (8 + 3 * q) * 64;
                    float4 xa = LD4(x1), xbv = LD4(x1 + 64), xc = LD4(x1 + 128);
                    float4 b0 = LD4(wa), b1 = LD4(wa + 16),
                           b2 = LD4(wa + 32), b3 = LD4(wa + 48);
                    fma4(acc[1], xa.x, b0); fma4(acc[2], xa.y, b0); fma4(acc[3], xa.z, b0);
                    fma4(acc[1], xa.w, b1); fma4(acc[2], xbv.x, b1); fma4(acc[3], xbv.y, b1);
                    fma4(acc[1], xbv.z, b2); fma4(acc[2], xbv.w, b2); fma4(acc[3], xc.x, b2);
                    fma4(acc[1], xc.y, b3); fma4(acc[2], xc.z, b3); fma4(acc[3], xc.w, b3);
                }
                {   // l2 -> acc[4..8]
                    const int wa = wq + 4096 + q * 64;
                    const int x2 = xo + (32 + 5 * q) * 64;
                    float4 xa = LD4(x2), xbv = LD4(x2 + 64), xc = LD4(x2 + 128),
                           xd = LD4(x2 + 192), xe = LD4(x2 + 256);
                    float4 c0 = LD4(wa), c1 = LD4(wa + 16),
                           c2 = LD4(wa + 32), c3 = LD4(wa + 48);
                    fma4(acc[4], xa.x, c0); fma4(acc[5], xa.y, c0); fma4(acc[6], xa.z, c0);
                    fma4(acc[7], xa.w, c0); fma4(acc[8], xbv.x, c0);
                    fma4(acc[4], xbv.y, c1); fma4(acc[5], xbv.z, c1); fma4(acc[6], xbv.w, c1);
                    fma4(acc[7], xc.x, c1); fma4(acc[8], xc.y, c1);
                    fma4(acc[4], xc.z, c2); fma4(acc[5], xc.w, c2); fma4(acc[6], xd.x, c2);
                    fma4(acc[7], xd.y, c2); fma4(acc[8], xd.z, c2);
                    fma4(acc[4], xd.w, c3); fma4(acc[5], xe.x, c3); fma4(acc[6], xe.y, c3);
                    fma4(acc[7], xe.z, c3); fma4(acc[8], xe.w, c3);
                }
            }

            // epilogue BEFORE issue(s+2): atomics stay older than the prefetch,
            // so the next stage's vmcnt(W) drains them without touching it.
            if (ch == 3) {
                const int n = rowbase + rg * 16 + r;
                float* op = out + ((size_t)n * 16 + oq * 4) * 9;
#pragma unroll
                for (int col = 0; col < 9; ++col) {
                    atomicAdd(op +  0 + col, acc[col].x * sc);
                    atomicAdd(op +  9 + col, acc[col].y * sc);
                    atomicAdd(op + 18 + col, acc[col].z * sc);
                    atomicAdd(op + 27 + col, acc[col].w * sc);
                }
            }

            if (s + 2 < NSTG) issue(s + 2, (buf + 2) % 3);
            buf = (buf + 1 == 3) ? 0 : buf + 1;
        }
    }
#undef LD4
}

extern "C" void kernel_launch(void* const* d_in, const int* in_sizes, int n_in,
                              void* d_out, int out_size, void* d_ws, size_t ws_size,
                              hipStream_t stream) {
    (void)in_sizes; (void)n_in; (void)d_ws; (void)ws_size;
    hipMemsetAsync(d_out, 0, (size_t)out_size * sizeof(float), stream);
    glin_fused<<<512, 256, 0, stream>>>((const float*)d_in[0], (const float*)d_in[1],
                                        (const float*)d_in[2], (const float*)d_in[3],
                                        (float*)d_out);
}

// Round 2
// 455.652 us; speedup vs baseline: 5.5128x; 5.5128x over previous
//
#include <hip/hip_runtime.h>

// GeneralLinear: x[8192,16,576] fp32 -> out[8192,16,9] fp32.
// out[n,o,col_l(e)] = (1/32) * sum_{c,u} x[n, c, off_l + u*d_l + e] * w_l[c*64+u, o]
//
// R6: single-owner blocks, zero global reduction, zero workspace.
//  - 512 blocks x 16 rows. Each block reduces over ALL 16 channels and ALL
//    64 u in-block -> every out cell written exactly once by plain stores.
//    (R5 lesson: 32-way atomicAdd = 2.4 GB HBM writes; R4 lesson: using d_ws
//    costs a ~181 us harness poison-fill. This uses neither.)
//  - Stage s = (c = s>>1, g = s&1): x u-half slice (4608 fl, 18 DMAs, gather
//    into [72 qc][16 r][4] col-major-float4 layout, 2-way bank alias = free)
//    + w slice rows c*64+32g..+32 of each w_l (1536 fl, 6 contiguous DMAs).
//    Exactly 6 DMA instrs per wave per stage -> uniform counted vmcnt.
//  - 3 stage buffers (72 KB LDS), depth-2 prefetch. Per stage:
//    s_waitcnt vmcnt(6) -> s_barrier -> issue(s+2) -> compute. vmcnt never
//    drains to 0 inside the loop. issue-before-compute gives DMA ~2 stages
//    of latency cover; buffer (s+2)%3 == (s-1)%3 is provably dead after the
//    barrier (all waves passed compute(s-1)).
//  - Epilogue once per block: acc -> LDS (reusing dead stage buffers),
//    4-wave tree sum, wave 0 writes 36 contiguous floats per (n,oq) quad.

#define DIN   576
#define XROW  (16 * DIN)          // 9216 floats per x row
#define NSTG  32                  // 16 channels x 2 u-halves
#define SFL   6144                // stage buffer floats (x 4608 + w 1536)
#define WREL  4608                // w offset within stage buffer
#define LDSF  (3 * SFL)           // 18432 floats = 73728 B -> 2 blocks/CU

__device__ __forceinline__ void dma16(const float* g, float* l) {
    __builtin_amdgcn_global_load_lds(
        (const __attribute__((address_space(1))) void*)g,
        (__attribute__((address_space(3))) void*)l, 16, 0, 0);
}

__device__ __forceinline__ void fma4(float4& a, float s, const float4 w) {
    a.x += s * w.x; a.y += s * w.y; a.z += s * w.z; a.w += s * w.w;
}

__global__ __launch_bounds__(256, 2) void glin_onepass(
    const float* __restrict__ x,
    const float* __restrict__ w0,
    const float* __restrict__ w1,
    const float* __restrict__ w2,
    float* __restrict__ out)
{
    __shared__ __align__(16) float lds[LDSF];
#define LD4(i) (*(const float4*)&lds[(i)])

    const int tid  = threadIdx.x;
    const int lane = tid & 63;
    const int wv   = tid >> 6;
    const int r    = lane & 15;    // row within block
    const int oq   = lane >> 4;    // output quad (o = oq*4 + j)
    const int rowbase = blockIdx.x * 16;

    const float* xrow = x + (size_t)(rowbase + r) * XROW;

    // 24 DMA instrs per stage, exactly 6 per wave:
    //   x (18): i = wv+4k (k=0..3) for all waves, + i=16 (wv2), i=17 (wv3)
    //   w (6):  wv0: w0 h0,h1 | wv1: w1 h0,h1 | wv2: w2 h0 | wv3: w2 h1
    auto issue = [&](int s) {
        const int c = s >> 1, g = s & 1;
        float* db = &lds[(s % 3) * SFL];
        const float* xb = xrow + c * DIN;
#pragma unroll
        for (int k = 0; k < 4; ++k) {
            const int i  = wv + 4 * k;
            const int qc = i * 4 + oq, lc = qc * 4;
            const int col = (qc < 8)  ? (32 * g + lc)          // l0 u-half
                          : (qc < 32) ? (32 + 96 * g + lc)     // l1 u-half
                                      : (128 + 160 * g + lc);  // l2 u-half
            dma16(xb + col, db + i * 256);
        }
        if (wv >= 2) {
            const int i  = 14 + wv;                            // 16, 17
            const int lc = (i * 4 + oq) * 4;
            dma16(xb + 128 + 160 * g + lc, db + i * 256);      // l2 tail
        }
        const float* wsrc = (wv == 0) ? w0 : (wv == 1) ? w1 : w2;
        const int wbase = (c * 64 + 32 * g) * 16 + lane * 4;
        if (wv < 2) {
            float* wd = db + WREL + wv * 512;
            dma16(wsrc + wbase,       wd);
            dma16(wsrc + wbase + 256, wd + 256);
        } else {
            const int h = wv - 2;
            dma16(wsrc + wbase + h * 256, db + WREL + 1024 + h * 256);
        }
    };

    issue(0);
    issue(1);

    float4 acc[9];
#pragma unroll
    for (int i = 0; i < 9; ++i) acc[i] = make_float4(0.f, 0.f, 0.f, 0.f);

    for (int s = 0; s < NSTG; ++s) {
        // certify OWN stage-s DMAs landed, then align all waves: after the
        // barrier every wave's stage-s loads are complete (vmcnt is per-wave).
        if (s == NSTG - 1) asm volatile("s_waitcnt vmcnt(0)" ::: "memory");
        else               asm volatile("s_waitcnt vmcnt(6)" ::: "memory");
        __builtin_amdgcn_s_barrier();
        asm volatile("" ::: "memory");

        if (s + 2 < NSTG) issue(s + 2);   // into dead buffer (s-1)%3

        const int bufo = (s % 3) * SFL;
        const int xo = bufo + r * 4;
        const int wq = bufo + WREL + oq * 4;
#pragma unroll
        for (int qq = 0; qq < 2; ++qq) {
            const int q = wv * 2 + qq;     // u = 32g + 4q + i
            {   // l0 -> acc[0]
                const int wa = wq + q * 64;
                float4 xq = LD4(xo + q * 64);
                float4 a0 = LD4(wa), a1 = LD4(wa + 16),
                       a2 = LD4(wa + 32), a3 = LD4(wa + 48);
                fma4(acc[0], xq.x, a0); fma4(acc[0], xq.y, a1);
                fma4(acc[0], xq.z, a2); fma4(acc[0], xq.w, a3);
            }
            {   // l1 -> acc[1..3]
                const int wa = wq + 512 + q * 64;
                const int x1 = xo + (8 + 3 * q) * 64;
                float4 xa = LD4(x1), xbv = LD4(x1 + 64), xc = LD4(x1 + 128);
                float4 b0 = LD4(wa), b1 = LD4(wa + 16),
                       b2 = LD4(wa + 32), b3 = LD4(wa + 48);
                fma4(acc[1], xa.x, b0); fma4(acc[2], xa.y, b0); fma4(acc[3], xa.z, b0);
                fma4(acc[1], xa.w, b1); fma4(acc[2], xbv.x, b1); fma4(acc[3], xbv.y, b1);
                fma4(acc[1], xbv.z, b2); fma4(acc[2], xbv.w, b2); fma4(acc[3], xc.x, b2);
                fma4(acc[1], xc.y, b3); fma4(acc[2], xc.z, b3); fma4(acc[3], xc.w, b3);
            }
            {   // l2 -> acc[4..8]
                const int wa = wq + 1024 + q * 64;
                const int x2 = xo + (32 + 5 * q) * 64;
                float4 xa = LD4(x2), xbv = LD4(x2 + 64), xc = LD4(x2 + 128),
                       xd = LD4(x2 + 192), xe = LD4(x2 + 256);
                float4 c0 = LD4(wa), c1 = LD4(wa + 16),
                       c2 = LD4(wa + 32), c3 = LD4(wa + 48);
                fma4(acc[4], xa.x, c0); fma4(acc[5], xa.y, c0); fma4(acc[6], xa.z, c0);
                fma4(acc[7], xa.w, c0); fma4(acc[8], xbv.x, c0);
                fma4(acc[4], xbv.y, c1); fma4(acc[5], xbv.z, c1); fma4(acc[6], xbv.w, c1);
                fma4(acc[7], xc.x, c1); fma4(acc[8], xc.y, c1);
                fma4(acc[4], xc.z, c2); fma4(acc[5], xc.w, c2); fma4(acc[6], xd.x, c2);
                fma4(acc[7], xd.y, c2); fma4(acc[8], xd.z, c2);
                fma4(acc[4], xd.w, c3); fma4(acc[5], xe.x, c3); fma4(acc[6], xe.y, c3);
                fma4(acc[7], xe.z, c3); fma4(acc[8], xe.w, c3);
            }
        }
    }

    // ---- once-per-block epilogue: 4-wave reduction + single-owner store ----
    __syncthreads();                       // stage buffers now dead
#pragma unroll
    for (int col = 0; col < 9; ++col)
        *(float4*)&lds[(tid * 9 + col) * 4] = acc[col];
    __syncthreads();
    if (wv == 0) {
        const float sc = 1.0f / 32.0f;
        float f[36];
#pragma unroll
        for (int col = 0; col < 9; ++col) {
            float4 v0 = LD4(((  0 + lane) * 9 + col) * 4);
            float4 v1 = LD4((( 64 + lane) * 9 + col) * 4);
            float4 v2 = LD4(((128 + lane) * 9 + col) * 4);
            float4 v3 = LD4(((192 + lane) * 9 + col) * 4);
            f[0 * 9 + col] = (v0.x + v1.x + v2.x + v3.x) * sc;
            f[1 * 9 + col] = (v0.y + v1.y + v2.y + v3.y) * sc;
            f[2 * 9 + col] = (v0.z + v1.z + v2.z + v3.z) * sc;
            f[3 * 9 + col] = (v0.w + v1.w + v2.w + v3.w) * sc;
        }
        float* op = out + ((size_t)(rowbase + r) * 16 + oq * 4) * 9;
#pragma unroll
        for (int k = 0; k < 9; ++k)
            *(float4*)&op[k * 4] =
                make_float4(f[4 * k], f[4 * k + 1], f[4 * k + 2], f[4 * k + 3]);
    }
#undef LD4
}

extern "C" void kernel_launch(void* const* d_in, const int* in_sizes, int n_in,
                              void* d_out, int out_size, void* d_ws, size_t ws_size,
                              hipStream_t stream) {
    (void)in_sizes; (void)n_in; (void)d_ws; (void)ws_size; (void)out_size;
    glin_onepass<<<512, 256, 0, stream>>>((const float*)d_in[0], (const float*)d_in[1],
                                          (const float*)d_in[2], (const float*)d_in[3],
                                          (float*)d_out);
}

// Round 4
// 434.703 us; speedup vs baseline: 5.7785x; 1.0482x over previous
//
#include <hip/hip_runtime.h>

// GeneralLinear: x[8192,16,576] fp32 -> out[8192,16,9] fp32.
// out[n,o,col_l(e)] = (1/32) * sum_{c,u} x[n, c, off_l + u*d_l + e] * w_l[c*64+u, o]
//
// R8 = R7 with the epilogue LDS-overflow bug fixed (slot stride 37 -> 9 float4;
// 256 slots x 9 x 16 B = 36864 B fits the 39936 B allocation; stride-9 writes
// are bandwidth-minimal anyway: 8 bank-quad groups x 8 lanes = 8 phases).
//
// Structure (R7): 4 blocks/CU, 16 waves/CU.
//  - 1024 blocks x 8 rows = EXACTLY 4/CU resident (no tail). LDS 39.9 KB.
//  - Thread = (r = lane&7, qs = lane>>3&1, oq = lane>>4); owns ONE u-quad
//    q = wv*2+qs per stage.
//  - Stage s = (c = s>>1, g = s&1): x u-half (2304 fl, 9 DMAs -> [72 qc][8 r][4],
//    128 B contiguous per row per instr) + w half (1536 fl, 6 DMAs).
//    x: 3 buffers, depth-2 prefetch (covers ~900 cyc HBM latency).
//    w: 2 buffers, depth-1 (L2-resident, ~200 cyc).
//  - Per-wave counted waits: at stage t the outstanding queue (oldest->newest)
//    is [x(t), w(t), x(t+1)]; wait vmcnt(n_x) keeps only x(t+1) in flight.
//    n_x = {3,2,2,2} per wave. vmcnt(0) only at s=31.
//    Body order: wait -> barrier -> issue_w(t+1) -> issue_x(t+2) -> compute.
//  - Single-owner epilogue: 8 partials (wv x qs) reduced once per block in
//    LDS; plain float4 stores; no ws, no atomics, no memset.

#define DIN   576
#define XROW  (16 * DIN)      // 9216 floats per x row
#define NSTG  32              // 16 channels x 2 u-halves
#define XSFL  2304            // x stage buffer floats (72 qc x 8 r x 4)
#define WSFL  1536            // w stage buffer floats (3 l x 32 lu x 16 o)
#define WB0   (3 * XSFL)      // 6912: w buffers after 3 x buffers
#define LDSF  (WB0 + 2 * WSFL) // 9984 floats = 39936 B -> 4 blocks/CU

__device__ __forceinline__ void dma16(const float* g, float* l) {
    __builtin_amdgcn_global_load_lds(
        (const __attribute__((address_space(1))) void*)g,
        (__attribute__((address_space(3))) void*)l, 16, 0, 0);
}

__device__ __forceinline__ void fma4(float4& a, float s, const float4 w) {
    a.x += s * w.x; a.y += s * w.y; a.z += s * w.z; a.w += s * w.w;
}

__global__ __launch_bounds__(256, 4) void glin_hiocc(
    const float* __restrict__ x,
    const float* __restrict__ w0,
    const float* __restrict__ w1,
    const float* __restrict__ w2,
    float* __restrict__ out)
{
    __shared__ __align__(16) float lds[LDSF];
#define LD4(i) (*(const float4*)&lds[(i)])

    const int tid  = threadIdx.x;
    const int lane = tid & 63;
    const int wv   = tid >> 6;
    const int r    = lane & 7;          // row within block
    const int qs   = (lane >> 3) & 1;   // u-quad sub-index
    const int oq   = lane >> 4;         // output quad
    const int q    = wv * 2 + qs;       // u-quad 0..7 within the g-half
    const int rowbase = blockIdx.x * 8;

    const float* xrow = x + (size_t)(rowbase + r) * XROW;   // per-lane (row)

    // x stage: 9 instrs; wave wv issues {wv, wv+4} (+8 if wv==0). n_x={3,2,2,2}.
    auto issue_x = [&](int s) {
        const int c = s >> 1, g = s & 1;
        float* db = &lds[(s % 3) * XSFL];
        const float* xb = xrow + c * DIN;
#pragma unroll
        for (int k = 0; k < 2; ++k) {
            const int i  = wv + 4 * k;
            const int qc = i * 8 + (lane >> 3);
            const int col = (qc < 8)  ? (32 * g + 4 * qc)
                          : (qc < 32) ? (32 + 96 * g + 4 * qc)
                                      : (128 + 160 * g + 4 * qc);
            dma16(xb + col, db + i * 256);
        }
        if (wv == 0) {
            const int qc = 64 + (lane >> 3);
            dma16(xb + 128 + 160 * g + 4 * qc, db + 8 * 256);
        }
    };

    // w stage: 6 instrs (j -> l = j>>1, h = j&1); waves get {j0},{j1,j4},{j2,j5},{j3}.
    auto issue_w = [&](int s) {
        const int c = s >> 1, g = s & 1;
        float* wd = &lds[WB0 + (s & 1) * WSFL];
        const int wbase = (c * 64 + 32 * g) * 16 + lane * 4;
        auto one = [&](int j) {
            const int l = j >> 1, h = j & 1;
            const float* wl = (l == 0) ? w0 : (l == 1) ? w1 : w2;
            dma16(wl + wbase + h * 256, wd + l * 512 + h * 256);
        };
        one(wv);
        if (wv == 1) one(4);
        if (wv == 2) one(5);
    };

    issue_x(0);
    issue_w(0);
    issue_x(1);

    float4 acc[9];
#pragma unroll
    for (int i = 0; i < 9; ++i) acc[i] = make_float4(0.f, 0.f, 0.f, 0.f);

    for (int s = 0; s < NSTG; ++s) {
        // keep only x(s+1) in flight; certify x(s), w(s) landed (per-wave FIFO)
        if (s == NSTG - 1) asm volatile("s_waitcnt vmcnt(0)" ::: "memory");
        else if (wv == 0)  asm volatile("s_waitcnt vmcnt(3)" ::: "memory");
        else               asm volatile("s_waitcnt vmcnt(2)" ::: "memory");
        __builtin_amdgcn_s_barrier();
        asm volatile("" ::: "memory");

        if (s + 1 < NSTG) issue_w(s + 1);   // into dead w-buffer (s-1)&1
        if (s + 2 < NSTG) issue_x(s + 2);   // into dead x-buffer (s-1)%3

        const int xo = (s % 3) * XSFL + r * 4;
        const int wq = WB0 + (s & 1) * WSFL + oq * 4;
        {   // l0 -> acc[0]
            const int wa = wq + q * 64;
            float4 xq = LD4(xo + q * 32);
            float4 a0 = LD4(wa), a1 = LD4(wa + 16),
                   a2 = LD4(wa + 32), a3 = LD4(wa + 48);
            fma4(acc[0], xq.x, a0); fma4(acc[0], xq.y, a1);
            fma4(acc[0], xq.z, a2); fma4(acc[0], xq.w, a3);
        }
        {   // l1 -> acc[1..3]
            const int wa = wq + 512 + q * 64;
            const int x1 = xo + (8 + 3 * q) * 32;
            float4 xa = LD4(x1), xbv = LD4(x1 + 32), xc = LD4(x1 + 64);
            float4 b0 = LD4(wa), b1 = LD4(wa + 16),
                   b2 = LD4(wa + 32), b3 = LD4(wa + 48);
            fma4(acc[1], xa.x, b0); fma4(acc[2], xa.y, b0); fma4(acc[3], xa.z, b0);
            fma4(acc[1], xa.w, b1); fma4(acc[2], xbv.x, b1); fma4(acc[3], xbv.y, b1);
            fma4(acc[1], xbv.z, b2); fma4(acc[2], xbv.w, b2); fma4(acc[3], xc.x, b2);
            fma4(acc[1], xc.y, b3); fma4(acc[2], xc.z, b3); fma4(acc[3], xc.w, b3);
        }
        {   // l2 -> acc[4..8]
            const int wa = wq + 1024 + q * 64;
            const int x2 = xo + (32 + 5 * q) * 32;
            float4 xa = LD4(x2), xbv = LD4(x2 + 32), xc = LD4(x2 + 64),
                   xd = LD4(x2 + 96), xe = LD4(x2 + 128);
            float4 c0 = LD4(wa), c1 = LD4(wa + 16),
                   c2 = LD4(wa + 32), c3 = LD4(wa + 48);
            fma4(acc[4], xa.x, c0); fma4(acc[5], xa.y, c0); fma4(acc[6], xa.z, c0);
            fma4(acc[7], xa.w, c0); fma4(acc[8], xbv.x, c0);
            fma4(acc[4], xbv.y, c1); fma4(acc[5], xbv.z, c1); fma4(acc[6], xbv.w, c1);
            fma4(acc[7], xc.x, c1); fma4(acc[8], xc.y, c1);
            fma4(acc[4], xc.z, c2); fma4(acc[5], xc.w, c2); fma4(acc[6], xd.x, c2);
            fma4(acc[7], xd.y, c2); fma4(acc[8], xd.z, c2);
            fma4(acc[4], xd.w, c3); fma4(acc[5], xe.x, c3); fma4(acc[6], xe.y, c3);
            fma4(acc[7], xe.z, c3); fma4(acc[8], xe.w, c3);
        }
    }

    // ---- once-per-block epilogue: 8-partial reduction + single-owner store ----
    // Slot stride 9 float4: 256 slots x 9 x 16 B = 36864 B <= 39936 B LDS.
    // Wave writes: 8 bank-quad groups x 8 lanes = 8 phases = BW minimum (free).
    __syncthreads();                       // all stage buffers dead
    {
        const int slot = (q * 8 + r) * 4 + oq;   // 0..255, unique per thread
#pragma unroll
        for (int col = 0; col < 9; ++col)
            *(float4*)&lds[(slot * 9 + col) * 4] = acc[col];
    }
    __syncthreads();
    if (wv == 0 && lane < 32) {
        const int rr = lane & 7, oqq = lane >> 3;
        const float sc = 1.0f / 32.0f;
        float f[36];
#pragma unroll
        for (int col = 0; col < 9; ++col) {
            float4 v = make_float4(0.f, 0.f, 0.f, 0.f);
#pragma unroll
            for (int p = 0; p < 8; ++p) {
                float4 t = LD4(((((p * 8 + rr) * 4 + oqq) * 9) + col) * 4);
                v.x += t.x; v.y += t.y; v.z += t.z; v.w += t.w;
            }
            f[0 * 9 + col] = v.x * sc;
            f[1 * 9 + col] = v.y * sc;
            f[2 * 9 + col] = v.z * sc;
            f[3 * 9 + col] = v.w * sc;
        }
        float* op = out + ((size_t)(rowbase + rr) * 16 + oqq * 4) * 9;
#pragma unroll
        for (int k = 0; k < 9; ++k)
            *(float4*)&op[k * 4] =
                make_float4(f[4 * k], f[4 * k + 1], f[4 * k + 2], f[4 * k + 3]);
    }
#undef LD4
}

extern "C" void kernel_launch(void* const* d_in, const int* in_sizes, int n_in,
                              void* d_out, int out_size, void* d_ws, size_t ws_size,
                              hipStream_t stream) {
    (void)in_sizes; (void)n_in; (void)d_ws; (void)ws_size; (void)out_size;
    glin_hiocc<<<1024, 256, 0, stream>>>((const float*)d_in[0], (const float*)d_in[1],
                                         (const float*)d_in[2], (const float*)d_in[3],
                                         (float*)d_out);
}